// Round 5
// baseline (1788.277 us; speedup 1.0000x reference)
//
#include <hip/hip_runtime.h>
#include <stdint.h>

#define N_NODES 50000
#define N_EDGES 800000
#define D_IN    788
#define D_INP   800   // K padded to 25*32
#define D_HID   256
#define N_REL   7
#define NBINS   (N_REL * N_NODES)   // 350000
#define NSCANB  342                 // ceil(350000/1024)

typedef __attribute__((ext_vector_type(8))) short bf16x8;
typedef __attribute__((ext_vector_type(4))) float f32x4;
typedef __attribute__((ext_vector_type(4))) unsigned int u32x4;

__device__ __forceinline__ unsigned short f2bf(float f) {
  union { float f; unsigned int u; } v; v.f = f;
  unsigned int u = v.u;
  return (unsigned short)((u + 0x7fffu + ((u >> 16) & 1u)) >> 16);
}

// ---- x (N,788) fp32 -> xb (N,800) bf16, zero-padded K ----
__global__ void k_cast_x(const float* __restrict__ x, unsigned short* __restrict__ xb) {
  int t = blockIdx.x * blockDim.x + threadIdx.x;
  if (t >= N_NODES * 200) return;
  int row = t / 200, k = (t % 200) * 4;
  ushort4 o = {0, 0, 0, 0};
  if (k < D_IN) {
    float4 v = *(const float4*)(x + (size_t)row * D_IN + k);
    o.x = f2bf(v.x); o.y = f2bf(v.y); o.z = f2bf(v.z); o.w = f2bf(v.w);
  }
  *(ushort4*)(xb + (size_t)row * D_INP + k) = o;
}

// ---- weights -> bf16, transposed to [mat][o][k], K padded ----
__global__ void k_conv_w(const float* __restrict__ w_rel, const float* __restrict__ w_root,
                         unsigned short* __restrict__ wt) {
  int t = blockIdx.x * blockDim.x + threadIdx.x;
  if (t >= 8 * D_HID * D_INP) return;
  int m = t / (D_HID * D_INP);
  int rem = t % (D_HID * D_INP);
  int o = rem / D_INP, k = rem % D_INP;
  float v = 0.f;
  if (k < D_IN) {
    const float* src = (m < N_REL) ? (w_rel + (size_t)m * D_IN * D_HID) : w_root;
    v = src[(size_t)k * D_HID + o];
  }
  wt[t] = f2bf(v);
}

// ---- per-(rel,dst) edge counts + per-rel histogram (block-local) ----
__global__ void k_count(const int* __restrict__ etype, const int* __restrict__ edst,
                        int* __restrict__ cnt, int* __restrict__ relc) {
  __shared__ int lh[N_REL];
  int tid = threadIdx.x;
  if (tid < N_REL) lh[tid] = 0;
  __syncthreads();
  int t = blockIdx.x * blockDim.x + tid;
  if (t < N_EDGES) {
    int et = etype[t], d = edst[t];
    atomicAdd(&cnt[et * N_NODES + d], 1);
    atomicAdd(&lh[et], 1);
  }
  __syncthreads();
  if (tid < N_REL && lh[tid] > 0) atomicAdd(&relc[tid], lh[tid]);
}

// ---- 128-aligned section bases: rb[0..8] ----
__global__ void k_scan(const int* __restrict__ relc, int* __restrict__ rb) {
  rb[0] = 0;
  for (int r = 0; r < N_REL; r++)
    rb[r + 1] = rb[r] + (((relc[r] + 127) >> 7) << 7);
  rb[8] = rb[7] + (((N_NODES + 127) >> 7) << 7);
}

__global__ void k_inv(const int* __restrict__ cnt, float* __restrict__ inv) {
  int t = blockIdx.x * blockDim.x + threadIdx.x;
  if (t >= NBINS) return;
  int c = cnt[t];
  inv[t] = 1.0f / (float)(c > 1 ? c : 1);
}

// ==== exclusive scan of cnt[350000] -> S (3 kernels) ====
__global__ void k_scan1(const int* __restrict__ cnt, int* __restrict__ bsum) {
  __shared__ int wsh[4];
  int b = blockIdx.x, tid = threadIdx.x;
  int base = b * 1024 + tid * 4;
  int4 v = {0, 0, 0, 0};
  if (base + 3 < NBINS) v = *(const int4*)(cnt + base);
  else { for (int i = 0; i < 4; i++) if (base + i < NBINS) ((int*)&v)[i] = cnt[base + i]; }
  int s = v.x + v.y + v.z + v.w;
  for (int o = 32; o > 0; o >>= 1) s += __shfl_down(s, o);
  if ((tid & 63) == 0) wsh[tid >> 6] = s;
  __syncthreads();
  if (tid == 0) bsum[b] = wsh[0] + wsh[1] + wsh[2] + wsh[3];
}

__global__ void k_scan2(const int* __restrict__ bsum, int* __restrict__ boff) {
  __shared__ int tmp[512];
  int tid = threadIdx.x;
  int mine = (tid < NSCANB) ? bsum[tid] : 0;
  tmp[tid] = mine;
  __syncthreads();
  for (int o = 1; o < 512; o <<= 1) {
    int v = (tid >= o) ? tmp[tid - o] : 0;
    __syncthreads();
    tmp[tid] += v;
    __syncthreads();
  }
  if (tid < NSCANB) boff[tid] = tmp[tid] - mine;   // exclusive
}

__global__ void k_scan3(const int* __restrict__ cnt, const int* __restrict__ boff,
                        int* __restrict__ S) {
  __shared__ int wsum[4];
  int b = blockIdx.x, tid = threadIdx.x;
  int base = b * 1024 + tid * 4;
  int4 v = {0, 0, 0, 0};
  if (base + 3 < NBINS) v = *(const int4*)(cnt + base);
  else { for (int i = 0; i < 4; i++) if (base + i < NBINS) ((int*)&v)[i] = cnt[base + i]; }
  int s = v.x + v.y + v.z + v.w;
  int lane = tid & 63, w = tid >> 6;
  int sc = s;
  for (int o = 1; o < 64; o <<= 1) { int u = __shfl_up(sc, o); if (lane >= o) sc += u; }
  if (lane == 63) wsum[w] = sc;
  __syncthreads();
  int wbase = 0;
  for (int i = 0; i < w; i++) wbase += wsum[i];
  int excl = boff[b] + wbase + sc - s;
  int o0 = excl, o1 = excl + v.x, o2 = o1 + v.y, o3 = o2 + v.z;
  if (base + 3 < NBINS) { int4 o4 = {o0, o1, o2, o3}; *(int4*)(S + base) = o4; }
  else {
    if (base     < NBINS) S[base]     = o0;
    if (base + 1 < NBINS) S[base + 1] = o1;
    if (base + 2 < NBINS) S[base + 2] = o2;
    if (base + 3 < NBINS) S[base + 3] = o3;
  }
}

// ---- scatter edges into perm, sorted by (rel, dst) via bin offsets ----
__global__ void k_scatter(const int* __restrict__ etype, const int* __restrict__ edst,
                          const int* __restrict__ S, const int* __restrict__ rb,
                          int* __restrict__ rank, int* __restrict__ perm) {
  int t = blockIdx.x * blockDim.x + threadIdx.x;
  if (t >= N_EDGES) return;
  int et = etype[t], d = edst[t];
  int r = atomicAdd(&rank[et * N_NODES + d], 1);
  int pos = S[et * N_NODES + d] - S[et * N_NODES] + r;
  perm[rb[et] + pos] = t;
}

// ---- grouped gathered GEMM: 128x256 tile, 4 waves (each 128x64).
// NO LDS staging, NO K-loop barriers: A and B fragments are loaded per-lane
// directly from global in MFMA operand layout (A: row=lane&15, k=quad*8+j).
// Pointers precomputed; K-loop fully unrolled so every load uses a constant
// offset immediate (ks*64 B < 4096) -- flat dependency graph the compiler can
// software-pipeline with fine-grained vmcnt(N). B is L2-resident (3.3 MB);
// A's 64B/row/step chunks are shared across the block's 4 waves via L1.
__global__ __launch_bounds__(256) void k_gemm1(
    const unsigned short* __restrict__ xb, const unsigned short* __restrict__ wt,
    const int* __restrict__ perm, const int* __restrict__ rb,
    const int* __restrict__ relc, const float* __restrict__ inv,
    const int* __restrict__ esrc, const int* __restrict__ edst,
    float* __restrict__ out1) {
  __shared__ int s_rb[9];
  __shared__ int s_src[128];
  __shared__ int s_dst[128];
  __shared__ float s_sc[128];

  int tid = threadIdx.x;
  if (tid < 9) s_rb[tid] = rb[tid];
  __syncthreads();

  int tile0 = blockIdx.x * 128;
  if (tile0 >= s_rb[8]) return;
  int sec = 0;
  while (sec < 7 && tile0 >= s_rb[sec + 1]) sec++;
  int cnt_sec = (sec < N_REL) ? relc[sec] : N_NODES;
  int mg0 = tile0 - s_rb[sec];

  if (tid < 128) {
    int mg = mg0 + tid;
    int s = 0, d = -1; float sc = 0.f;
    if (mg < cnt_sec) {
      if (sec < N_REL) {
        int e = perm[tile0 + tid];
        s = esrc[e]; d = edst[e];
        sc = inv[sec * N_NODES + d];
      } else { s = mg; d = mg; sc = 1.f; }
    }
    s_src[tid] = s; s_dst[tid] = d; s_sc[tid] = sc;
  }
  __syncthreads();

  const unsigned short* wsec = wt + (size_t)sec * (D_HID * D_INP);
  int lane = tid & 63, w = tid >> 6;
  int wn = w * 64;
  int row = lane & 15, quad = lane >> 4;

  // per-lane fragment pointers (constant through the K-loop)
  const unsigned short* ap[8];
#pragma unroll
  for (int i = 0; i < 8; i++)
    ap[i] = xb + (size_t)s_src[i * 16 + row] * D_INP + quad * 8;
  const unsigned short* bp[4];
#pragma unroll
  for (int j = 0; j < 4; j++)
    bp[j] = wsec + (size_t)(wn + j * 16 + row) * D_INP + quad * 8;

  f32x4 acc[8][4];
#pragma unroll
  for (int i = 0; i < 8; i++)
#pragma unroll
    for (int j = 0; j < 4; j++) acc[i][j] = (f32x4){0.f, 0.f, 0.f, 0.f};

#pragma unroll
  for (int ks = 0; ks < 25; ks++) {
    bf16x8 af[8], bf[4];
#pragma unroll
    for (int i = 0; i < 8; i++) af[i] = *(const bf16x8*)(ap[i] + ks * 32);
#pragma unroll
    for (int j = 0; j < 4; j++) bf[j] = *(const bf16x8*)(bp[j] + ks * 32);
#pragma unroll
    for (int i = 0; i < 8; i++)
#pragma unroll
      for (int j = 0; j < 4; j++)
        acc[i][j] = __builtin_amdgcn_mfma_f32_16x16x32_bf16(af[i], bf[j], acc[i][j], 0, 0, 0);
  }

  // epilogue: C layout col=lane&15, row=(lane>>4)*4+reg; merge equal-dst runs in regs
  int col_l = lane & 15, rquad = lane >> 4;
#pragma unroll
  for (int i = 0; i < 8; i++) {
    int rbase = i * 16 + rquad * 4;
    int dd[4]; float ss[4];
#pragma unroll
    for (int r = 0; r < 4; r++) { dd[r] = s_dst[rbase + r]; ss[r] = s_sc[rbase + r]; }
#pragma unroll
    for (int j = 0; j < 4; j++) {
      int colg = wn + j * 16 + col_l;
      int cur = dd[0]; float cs = ss[0]; float run = acc[i][j][0];
#pragma unroll
      for (int r = 1; r < 4; r++) {
        if (dd[r] == cur) {
          run += acc[i][j][r];
        } else {
          if (cur >= 0) atomicAdd(out1 + (size_t)cur * D_HID + colg, run * cs);
          cur = dd[r]; cs = ss[r]; run = acc[i][j][r];
        }
      }
      if (cur >= 0) atomicAdd(out1 + (size_t)cur * D_HID + colg, run * cs);
    }
  }
}

// ---- fused: h = relu(out1 + b1) in place, then y[m][n][2] = h[n] . W2_m ----
__global__ __launch_bounds__(256) void k_hy(
    float* __restrict__ h, const float* __restrict__ b1,
    const float* __restrict__ w2rel, const float* __restrict__ w2root,
    float* __restrict__ y) {
  int n = blockIdx.x * 4 + (threadIdx.x >> 6);
  int lane = threadIdx.x & 63;
  if (n >= N_NODES) return;
  float4 hv = *(float4*)(h + (size_t)n * D_HID + lane * 4);
  float4 b = *(const float4*)(b1 + lane * 4);
  hv.x = fmaxf(hv.x + b.x, 0.f);
  hv.y = fmaxf(hv.y + b.y, 0.f);
  hv.z = fmaxf(hv.z + b.z, 0.f);
  hv.w = fmaxf(hv.w + b.w, 0.f);
  *(float4*)(h + (size_t)n * D_HID + lane * 4) = hv;
#pragma unroll
  for (int m = 0; m < 8; m++) {
    const float* wp = (m < N_REL) ? (w2rel + m * (D_HID * 2)) : w2root;
    float4 wa = *(const float4*)(wp + lane * 8);
    float4 wb = *(const float4*)(wp + lane * 8 + 4);
    float d0 = hv.x * wa.x + hv.y * wa.z + hv.z * wb.x + hv.w * wb.z;
    float d1 = hv.x * wa.y + hv.y * wa.w + hv.z * wb.y + hv.w * wb.w;
#pragma unroll
    for (int off = 32; off > 0; off >>= 1) {
      d0 += __shfl_down(d0, off);
      d1 += __shfl_down(d1, off);
    }
    if (lane == 0) {
      y[(size_t)m * (N_NODES * 2) + n * 2]     = d0;
      y[(size_t)m * (N_NODES * 2) + n * 2 + 1] = d1;
    }
  }
}

// ---- layer 2 edge accumulate: 8 B gather per edge + root/bias ----
__global__ void k_edge2(const float* __restrict__ y, const float* __restrict__ b2,
                        const int* __restrict__ esrc, const int* __restrict__ edst,
                        const int* __restrict__ etype, const float* __restrict__ inv,
                        float* __restrict__ out) {
  int t = blockIdx.x * blockDim.x + threadIdx.x;
  if (t < N_EDGES) {
    int et = etype[t], s = esrc[t], d = edst[t];
    float2 yv = *(const float2*)(y + (size_t)et * (N_NODES * 2) + s * 2);
    float sc = inv[et * N_NODES + d];
    atomicAdd(out + (size_t)d * 2,     sc * yv.x);
    atomicAdd(out + (size_t)d * 2 + 1, sc * yv.y);
  } else if (t < N_EDGES + N_NODES) {
    int n = t - N_EDGES;
    float2 yv = *(const float2*)(y + (size_t)7 * (N_NODES * 2) + n * 2);
    atomicAdd(out + (size_t)n * 2,     yv.x + b2[0]);
    atomicAdd(out + (size_t)n * 2 + 1, yv.y + b2[1]);
  }
}

// ---- workspace layout (bytes) ----
#define OFF_XB   0u            // 50000*800*2       = 80,000,000
#define OFF_WT   80000000u     // 8*256*800*2       =  3,276,800
#define OFF_OUT1 83276800u     // 50000*256*4       = 51,200,000
#define OFF_CNT  134476800u    // 350000*4          =  1,400,000  (reused as rank after scan)
#define OFF_RELC 135876800u    // 8*4
#define OFF_RB   135876832u    // 16*4
#define OFF_CUR  135876896u    // 8*4 (kept for memset span)
#define OFF_INV  135876928u    // 350000*4          =  1,400,000
#define OFF_PERM 137276928u    // (800000+896)*4    =  3,203,584
#define OFF_Y    140480512u    // 8*50000*2*4       =  3,200,000
#define OFF_S    143680512u    // 350000*4          =  1,400,000
#define OFF_BSUM 145080512u    // 2048
#define OFF_BOFF 145082560u    // 2048
// total: 145,084,608 bytes

extern "C" void kernel_launch(void* const* d_in, const int* in_sizes, int n_in,
                              void* d_out, int out_size, void* d_ws, size_t ws_size,
                              hipStream_t stream) {
  const float* x      = (const float*)d_in[0];
  const int*   eidx   = (const int*)d_in[1];
  const int*   etype  = (const int*)d_in[2];
  const float* w1rel  = (const float*)d_in[3];
  const float* w1root = (const float*)d_in[4];
  const float* b1     = (const float*)d_in[5];
  const float* w2rel  = (const float*)d_in[6];
  const float* w2root = (const float*)d_in[7];
  const float* b2     = (const float*)d_in[8];
  float* out = (float*)d_out;
  char* ws = (char*)d_ws;

  unsigned short* xb = (unsigned short*)(ws + OFF_XB);
  unsigned short* wt = (unsigned short*)(ws + OFF_WT);
  float* out1 = (float*)(ws + OFF_OUT1);
  int*   cnt  = (int*)(ws + OFF_CNT);
  int*   relc = (int*)(ws + OFF_RELC);
  int*   rb   = (int*)(ws + OFF_RB);
  float* inv  = (float*)(ws + OFF_INV);
  int*   perm = (int*)(ws + OFF_PERM);
  float* y    = (float*)(ws + OFF_Y);
  int*   S    = (int*)(ws + OFF_S);
  int*   bsum = (int*)(ws + OFF_BSUM);
  int*   boff = (int*)(ws + OFF_BOFF);
  const int* esrc = eidx;
  const int* edst = eidx + N_EDGES;

  hipMemsetAsync(ws + OFF_OUT1, 0, 52600128u, stream);
  hipMemsetAsync(d_out, 0, (size_t)out_size * sizeof(float), stream);

  k_cast_x<<<(N_NODES * 200 + 255) / 256, 256, 0, stream>>>(x, xb);
  k_conv_w<<<(8 * D_HID * D_INP + 255) / 256, 256, 0, stream>>>(w1rel, w1root, wt);
  k_count<<<(N_EDGES + 255) / 256, 256, 0, stream>>>(etype, edst, cnt, relc);
  k_scan<<<1, 1, 0, stream>>>(relc, rb);
  k_inv<<<(NBINS + 255) / 256, 256, 0, stream>>>(cnt, inv);

  k_scan1<<<NSCANB, 256, 0, stream>>>(cnt, bsum);
  k_scan2<<<1, 512, 0, stream>>>(bsum, boff);
  k_scan3<<<NSCANB, 256, 0, stream>>>(cnt, boff, S);

  hipMemsetAsync(ws + OFF_CNT, 0, 1400000u, stream);
  k_scatter<<<(N_EDGES + 255) / 256, 256, 0, stream>>>(etype, edst, S, rb, cnt, perm);

  // worst-case 128-row M-tiles: (800000 + 7*128 + 50048) / 128 = 6648
  k_gemm1<<<6648, 256, 0, stream>>>(xb, wt, perm, rb, relc, inv, esrc, edst, out1);

  k_hy<<<(N_NODES + 3) / 4, 256, 0, stream>>>(out1, b1, w2rel, w2root, y);
  k_edge2<<<(N_EDGES + N_NODES + 255) / 256, 256, 0, stream>>>(y, b2, esrc, edst, etype, inv, out);
}

// Round 6
// 1046.691 us; speedup vs baseline: 1.7085x; 1.7085x over previous
//
#include <hip/hip_runtime.h>
#include <stdint.h>

#define N_NODES 50000
#define N_EDGES 800000
#define D_IN    788
#define D_INP   800   // K padded to 25*32 (weights only; x masked on the fly)
#define D_HID   256
#define N_REL   7
#define NBINS   (N_REL * N_NODES)   // 350000
#define NSCANB  342                 // ceil(350000/1024)

typedef __attribute__((ext_vector_type(8))) short bf16x8;
typedef __attribute__((ext_vector_type(4))) float f32x4;
typedef __attribute__((ext_vector_type(4))) unsigned int u32x4;

__device__ __forceinline__ unsigned short f2bf(float f) {
  union { float f; unsigned int u; } v; v.f = f;
  unsigned int u = v.u;
  return (unsigned short)((u + 0x7fffu + ((u >> 16) & 1u)) >> 16);
}

__device__ __forceinline__ f32x4 bf4(ushort4 g) {
  union { unsigned int u; float f; } a, b, c, d;
  a.u = (unsigned)g.x << 16; b.u = (unsigned)g.y << 16;
  c.u = (unsigned)g.z << 16; d.u = (unsigned)g.w << 16;
  return (f32x4){a.f, b.f, c.f, d.f};
}

// ---- weights -> bf16, transposed to [mat][o][k], K padded ----
// mat 0..6 = w1_rel[r] (788,256); mat 7 = w1_root
__global__ void k_conv_w(const float* __restrict__ w_rel, const float* __restrict__ w_root,
                         unsigned short* __restrict__ wt) {
  int t = blockIdx.x * blockDim.x + threadIdx.x;
  if (t >= 8 * D_HID * D_INP) return;
  int m = t / (D_HID * D_INP);
  int rem = t % (D_HID * D_INP);
  int o = rem / D_INP, k = rem % D_INP;
  float v = 0.f;
  if (k < D_IN) {
    const float* src = (m < N_REL) ? (w_rel + (size_t)m * D_IN * D_HID) : w_root;
    v = src[(size_t)k * D_HID + o];
  }
  wt[t] = f2bf(v);
}

// ---- per-(rel,dst) edge counts ----
__global__ void k_count(const int* __restrict__ etype, const int* __restrict__ edst,
                        int* __restrict__ cnt) {
  int t = blockIdx.x * blockDim.x + threadIdx.x;
  if (t >= N_EDGES) return;
  atomicAdd(&cnt[etype[t] * N_NODES + edst[t]], 1);
}

// ==== exclusive scan of cnt[350000] -> S (3 kernels) ====
__global__ void k_scan1(const int* __restrict__ cnt, int* __restrict__ bsum) {
  __shared__ int wsh[4];
  int b = blockIdx.x, tid = threadIdx.x;
  int base = b * 1024 + tid * 4;
  int4 v = {0, 0, 0, 0};
  if (base + 3 < NBINS) v = *(const int4*)(cnt + base);
  else { for (int i = 0; i < 4; i++) if (base + i < NBINS) ((int*)&v)[i] = cnt[base + i]; }
  int s = v.x + v.y + v.z + v.w;
  for (int o = 32; o > 0; o >>= 1) s += __shfl_down(s, o);
  if ((tid & 63) == 0) wsh[tid >> 6] = s;
  __syncthreads();
  if (tid == 0) bsum[b] = wsh[0] + wsh[1] + wsh[2] + wsh[3];
}

__global__ void k_scan2(const int* __restrict__ bsum, int* __restrict__ boff) {
  __shared__ int tmp[512];
  int tid = threadIdx.x;
  int mine = (tid < NSCANB) ? bsum[tid] : 0;
  tmp[tid] = mine;
  __syncthreads();
  for (int o = 1; o < 512; o <<= 1) {
    int v = (tid >= o) ? tmp[tid - o] : 0;
    __syncthreads();
    tmp[tid] += v;
    __syncthreads();
  }
  if (tid < NSCANB) boff[tid] = tmp[tid] - mine;   // exclusive
}

__global__ void k_scan3(const int* __restrict__ cnt, const int* __restrict__ boff,
                        int* __restrict__ S) {
  __shared__ int wsum[4];
  int b = blockIdx.x, tid = threadIdx.x;
  int base = b * 1024 + tid * 4;
  int4 v = {0, 0, 0, 0};
  if (base + 3 < NBINS) v = *(const int4*)(cnt + base);
  else { for (int i = 0; i < 4; i++) if (base + i < NBINS) ((int*)&v)[i] = cnt[base + i]; }
  int s = v.x + v.y + v.z + v.w;
  int lane = tid & 63, w = tid >> 6;
  int sc = s;
  for (int o = 1; o < 64; o <<= 1) { int u = __shfl_up(sc, o); if (lane >= o) sc += u; }
  if (lane == 63) wsum[w] = sc;
  __syncthreads();
  int wbase = 0;
  for (int i = 0; i < w; i++) wbase += wsum[i];
  int excl = boff[b] + wbase + sc - s;
  int o0 = excl, o1 = excl + v.x, o2 = o1 + v.y, o3 = o2 + v.z;
  if (base + 3 < NBINS) { int4 o4 = {o0, o1, o2, o3}; *(int4*)(S + base) = o4; }
  else {
    if (base     < NBINS) S[base]     = o0;
    if (base + 1 < NBINS) S[base + 1] = o1;
    if (base + 2 < NBINS) S[base + 2] = o2;
    if (base + 3 < NBINS) S[base + 3] = o3;
  }
}

// ---- scatter edge SOURCES into bin-sorted order ----
__global__ void k_scatter(const int* __restrict__ etype, const int* __restrict__ edst,
                          const int* __restrict__ esrc, const int* __restrict__ S,
                          int* __restrict__ rank, int* __restrict__ psrc) {
  int t = blockIdx.x * blockDim.x + threadIdx.x;
  if (t >= N_EDGES) return;
  int bin = etype[t] * N_NODES + edst[t];
  int r = atomicAdd(&rank[bin], 1);
  psrc[S[bin] + r] = esrc[t];
}

// ---- dense GEMM: xrel[m][n][o] = x[n] @ w[mat] for 2 mats per launch.
// 64x256 tile, 4 waves (each 64x64 of N). A read from fp32 x with on-the-fly
// bf16 convert + K-masking (k>=788 -> 0). Structure = proven R3 kernel
// (reg-prefetch + single-buffered LDS), minus gather, minus atomic epilogue.
__global__ __launch_bounds__(256) void k_gemm(
    const float* __restrict__ x, const unsigned short* __restrict__ wt,
    unsigned short* __restrict__ xrs, int mb) {
  __shared__ __align__(16) unsigned short As[64 * 40];    // stride 40: 2-way alias (free)
  __shared__ __align__(16) unsigned short Bs[256 * 40];

  int tid = threadIdx.x;
  int mat = mb + blockIdx.y;
  int m0 = blockIdx.x * 64;
  const unsigned short* wsec = wt + (size_t)mat * (D_HID * D_INP);
  int lane = tid & 63, w = tid >> 6;

  // staging: A row ra (0..63), k-chunk ca (8 vals); B rows ra+{0,64,128,192}
  int ra = tid >> 2, ca = tid & 3, ca8 = ca * 8;
  int arow = m0 + ra; if (arow > N_NODES - 1) arow = N_NODES - 1;
  const float* ap = x + (size_t)arow * D_IN;
  const unsigned short* bgp = wsec + (size_t)ra * D_INP + ca8;
  unsigned short* al = As + ra * 40 + ca8;
  unsigned short* bl = Bs + ra * 40 + ca8;

  f32x4 acc[4][4];
#pragma unroll
  for (int i = 0; i < 4; i++)
#pragma unroll
    for (int j = 0; j < 4; j++) acc[i][j] = (f32x4){0.f, 0.f, 0.f, 0.f};

  // prefetch step 0 (o = ca8 <= 24, no clamp)
  float4 pa0 = *(const float4*)(ap + ca8);
  float4 pa1 = *(const float4*)(ap + ca8 + 4);
  u32x4 pb0 = *(const u32x4*)(bgp);
  u32x4 pb1 = *(const u32x4*)(bgp +  64 * D_INP);
  u32x4 pb2 = *(const u32x4*)(bgp + 128 * D_INP);
  u32x4 pb3 = *(const u32x4*)(bgp + 192 * D_INP);

  int row = lane & 15, quad = lane >> 4;
  for (int ks = 0; ks < 25; ks++) {
    // pack A (mask k>=788) and store to LDS
    {
      int o = ks * 32 + ca8;
      float ld[16] = {pa0.x, pa0.y, pa0.z, pa0.w, pa1.x, pa1.y, pa1.z, pa1.w,
                      0.f, 0.f, 0.f, 0.f, 0.f, 0.f, 0.f, 0.f};
      int shift = (o > 780) ? (o - 780) : 0;
      union { unsigned short us[8]; u32x4 v; } pk;
#pragma unroll
      for (int j = 0; j < 8; j++)
        pk.us[j] = (o + j < D_IN) ? f2bf(ld[j + shift]) : (unsigned short)0;
      *(u32x4*)al = pk.v;
    }
    *(u32x4*)bl = pb0;
    *(u32x4*)(bl +  64 * 40) = pb1;
    *(u32x4*)(bl + 128 * 40) = pb2;
    *(u32x4*)(bl + 192 * 40) = pb3;
    __syncthreads();

    if (ks < 24) {
      int on = (ks + 1) * 32 + ca8;
      int lo = (on > 780) ? 780 : on;     // keep loads in-bounds; pack re-masks
      pa0 = *(const float4*)(ap + lo);
      pa1 = *(const float4*)(ap + lo + 4);
      int ko = (ks + 1) * 32;
      pb0 = *(const u32x4*)(bgp + ko);
      pb1 = *(const u32x4*)(bgp + ko +  64 * D_INP);
      pb2 = *(const u32x4*)(bgp + ko + 128 * D_INP);
      pb3 = *(const u32x4*)(bgp + ko + 192 * D_INP);
    }

    bf16x8 af[4], bfr[4];
#pragma unroll
    for (int i = 0; i < 4; i++)
      af[i] = *(const bf16x8*)(As + (i * 16 + row) * 40 + quad * 8);
#pragma unroll
    for (int j = 0; j < 4; j++)
      bfr[j] = *(const bf16x8*)(Bs + (w * 64 + j * 16 + row) * 40 + quad * 8);
#pragma unroll
    for (int i = 0; i < 4; i++)
#pragma unroll
      for (int j = 0; j < 4; j++)
        acc[i][j] = __builtin_amdgcn_mfma_f32_16x16x32_bf16(af[i], bfr[j], acc[i][j], 0, 0, 0);
    __syncthreads();
  }

  // epilogue: plain bf16 stores. C layout col=lane&15, row=(lane>>4)*4+reg
  int col_l = lane & 15, rquad = lane >> 4;
  unsigned short* xo = xrs + (size_t)blockIdx.y * ((size_t)N_NODES * D_HID);
#pragma unroll
  for (int i = 0; i < 4; i++) {
#pragma unroll
    for (int reg = 0; reg < 4; reg++) {
      int node = m0 + i * 16 + rquad * 4 + reg;
      if (node < N_NODES) {
#pragma unroll
        for (int j = 0; j < 4; j++)
          xo[(size_t)node * D_HID + w * 64 + j * 16 + col_l] = f2bf(acc[i][j][reg]);
      }
    }
  }
}

// ---- pull aggregation for layer 1 (no atomics). One wave per node.
// pass 0..2: rels {2p, 2p+1} accumulate into h. pass 3: rel 6 + root (slot 1)
// + bias + relu + fused layer-2 transform -> y[m][n][2].
__global__ __launch_bounds__(256) void k_agg(
    const unsigned short* __restrict__ xrs, const int* __restrict__ S,
    const int* __restrict__ cnt, const int* __restrict__ psrc,
    float* __restrict__ h, const float* __restrict__ b1,
    const float* __restrict__ w2rel, const float* __restrict__ w2root,
    float* __restrict__ y, int r0, int pass) {
  int n = blockIdx.x * 4 + (threadIdx.x >> 6);
  int lane = threadIdx.x & 63;
  if (n >= N_NODES) return;
  f32x4 acc;
  if (pass == 0) acc = (f32x4){0.f, 0.f, 0.f, 0.f};
  else acc = *(const f32x4*)(h + (size_t)n * D_HID + lane * 4);

  int nr = (pass < 3) ? 2 : 1;
  for (int rr = 0; rr < nr; rr++) {
    int bin = (r0 + rr) * N_NODES + n;
    int c = cnt[bin];
    if (c > 0) {
      int p = S[bin];
      f32x4 s = (f32x4){0.f, 0.f, 0.f, 0.f};
      int e = 0;
      for (; e + 1 < c; e += 2) {
        int s0 = psrc[p + e], s1 = psrc[p + e + 1];
        ushort4 g0 = *(const ushort4*)(xrs + ((size_t)rr * N_NODES + s0) * D_HID + lane * 4);
        ushort4 g1 = *(const ushort4*)(xrs + ((size_t)rr * N_NODES + s1) * D_HID + lane * 4);
        s += bf4(g0) + bf4(g1);
      }
      if (e < c) {
        int s0 = psrc[p + e];
        ushort4 g0 = *(const ushort4*)(xrs + ((size_t)rr * N_NODES + s0) * D_HID + lane * 4);
        s += bf4(g0);
      }
      acc += s * (1.0f / (float)c);
    }
  }

  if (pass < 3) {
    *(f32x4*)(h + (size_t)n * D_HID + lane * 4) = acc;
    return;
  }

  // final pass: root (slice slot 1) + bias + relu
  ushort4 gr = *(const ushort4*)(xrs + ((size_t)1 * N_NODES + n) * D_HID + lane * 4);
  acc += bf4(gr);
  f32x4 b = *(const f32x4*)(b1 + lane * 4);
  f32x4 hv;
  hv[0] = fmaxf(acc[0] + b[0], 0.f);
  hv[1] = fmaxf(acc[1] + b[1], 0.f);
  hv[2] = fmaxf(acc[2] + b[2], 0.f);
  hv[3] = fmaxf(acc[3] + b[3], 0.f);

  // fused layer-2 transform: y[m][n][2] = h[n] . W2_m
#pragma unroll
  for (int m = 0; m < 8; m++) {
    const float* wp = (m < N_REL) ? (w2rel + m * (D_HID * 2)) : w2root;
    f32x4 wa = *(const f32x4*)(wp + lane * 8);
    f32x4 wb = *(const f32x4*)(wp + lane * 8 + 4);
    float d0 = hv[0] * wa[0] + hv[1] * wa[2] + hv[2] * wb[0] + hv[3] * wb[2];
    float d1 = hv[0] * wa[1] + hv[1] * wa[3] + hv[2] * wb[1] + hv[3] * wb[3];
#pragma unroll
    for (int off = 32; off > 0; off >>= 1) {
      d0 += __shfl_down(d0, off);
      d1 += __shfl_down(d1, off);
    }
    if (lane == 0) {
      y[(size_t)m * (N_NODES * 2) + n * 2]     = d0;
      y[(size_t)m * (N_NODES * 2) + n * 2 + 1] = d1;
    }
  }
}

// ---- layer-2 aggregation: thread per bin (mean over bin) + root/bias threads ----
__global__ void k_out(const float* __restrict__ y, const float* __restrict__ b2,
                      const int* __restrict__ cnt, const int* __restrict__ S,
                      const int* __restrict__ psrc, float* __restrict__ out) {
  int t = blockIdx.x * blockDim.x + threadIdx.x;
  if (t < NBINS) {
    int c = cnt[t];
    if (c == 0) return;
    int p = S[t];
    int r = t / N_NODES;
    int i = t - r * N_NODES;
    const float* yr = y + (size_t)r * (N_NODES * 2);
    float s0 = 0.f, s1 = 0.f;
    for (int e = 0; e < c; e++) {
      int sc = psrc[p + e];
      float2 v = *(const float2*)(yr + sc * 2);
      s0 += v.x; s1 += v.y;
    }
    float is = 1.0f / (float)c;
    atomicAdd(out + (size_t)i * 2,     s0 * is);
    atomicAdd(out + (size_t)i * 2 + 1, s1 * is);
  } else if (t < NBINS + N_NODES) {
    int i = t - NBINS;
    float2 v = *(const float2*)(y + (size_t)N_REL * (N_NODES * 2) + i * 2);
    atomicAdd(out + (size_t)i * 2,     v.x + b2[0]);
    atomicAdd(out + (size_t)i * 2 + 1, v.y + b2[1]);
  }
}

// ---- workspace layout (bytes); total 116,280,896 (< proven 145 MB) ----
#define OFF_WT   0u            // 8*256*800*2       =  3,276,800
#define OFF_XRS  3276800u      // 2*50000*256*2     = 51,200,000
#define OFF_H    54476800u     // 50000*256*4       = 51,200,000
#define OFF_CNT  105676800u    // 350000*4          =  1,400,000
#define OFF_RANK 107076800u    // 350000*4          =  1,400,000
#define OFF_S    108476800u    // 350000*4          =  1,400,000
#define OFF_PSRC 109876800u    // 800000*4          =  3,200,000
#define OFF_Y    113076800u    // 8*50000*2*4       =  3,200,000
#define OFF_BSUM 116276800u    // 2048
#define OFF_BOFF 116278848u    // 2048

extern "C" void kernel_launch(void* const* d_in, const int* in_sizes, int n_in,
                              void* d_out, int out_size, void* d_ws, size_t ws_size,
                              hipStream_t stream) {
  const float* x      = (const float*)d_in[0];
  const int*   eidx   = (const int*)d_in[1];
  const int*   etype  = (const int*)d_in[2];
  const float* w1rel  = (const float*)d_in[3];
  const float* w1root = (const float*)d_in[4];
  const float* b1     = (const float*)d_in[5];
  const float* w2rel  = (const float*)d_in[6];
  const float* w2root = (const float*)d_in[7];
  const float* b2     = (const float*)d_in[8];
  float* out = (float*)d_out;
  char* ws = (char*)d_ws;

  unsigned short* wt  = (unsigned short*)(ws + OFF_WT);
  unsigned short* xrs = (unsigned short*)(ws + OFF_XRS);
  float* h    = (float*)(ws + OFF_H);
  int*   cnt  = (int*)(ws + OFF_CNT);
  int*   rank = (int*)(ws + OFF_RANK);
  int*   S    = (int*)(ws + OFF_S);
  int*   psrc = (int*)(ws + OFF_PSRC);
  float* y    = (float*)(ws + OFF_Y);
  int*   bsum = (int*)(ws + OFF_BSUM);
  int*   boff = (int*)(ws + OFF_BOFF);
  const int* esrc = eidx;
  const int* edst = eidx + N_EDGES;

  hipMemsetAsync(ws + OFF_CNT, 0, 2800000u, stream);           // cnt + rank
  hipMemsetAsync(d_out, 0, (size_t)out_size * sizeof(float), stream);

  k_conv_w<<<6400, 256, 0, stream>>>(w1rel, w1root, wt);
  k_count<<<(N_EDGES + 255) / 256, 256, 0, stream>>>(etype, edst, cnt);
  k_scan1<<<NSCANB, 256, 0, stream>>>(cnt, bsum);
  k_scan2<<<1, 512, 0, stream>>>(bsum, boff);
  k_scan3<<<NSCANB, 256, 0, stream>>>(cnt, boff, S);
  k_scatter<<<(N_EDGES + 255) / 256, 256, 0, stream>>>(etype, edst, esrc, S, rank, psrc);

  for (int p = 0; p < 4; p++) {
    k_gemm<<<dim3(782, 2), 256, 0, stream>>>(x, wt, xrs, 2 * p);
    k_agg<<<(N_NODES + 3) / 4, 256, 0, stream>>>(xrs, S, cnt, psrc, h,
                                                 b1, w2rel, w2root, y, 2 * p, p);
  }

  k_out<<<(NBINS + N_NODES + 255) / 256, 256, 0, stream>>>(y, b2, cnt, S, psrc, out);
}